// Round 11
// baseline (129.593 us; speedup 1.0000x reference)
//
#include <hip/hip_runtime.h>

// ============================================================================
// ev(b) = F1(b)^T * A * F2(b); A fixed (theta batch-uniform).
// ONE kernel; every block redundantly builds A in its own LDS (no ws, no
// flags, no second launch):
//   A. tables: TR[256] PTMs + CNOT conj table (parallel, spill-free).
//   B. S1 = Ring2^dag Z0 Ring2 (1 thread).
//   C. enumerate all (<=6561) post-ring strings ONCE into per-thread regs
//      (26 packed entries/thread, unrolled).
//   D. for each (P0,P1) in {I,Z,Y}^2 (9 rounds): project strings through
//      wire-0/wire-1 PTM rows -> scatter-add dense 4^6 LDS tensor ->
//      6-stage wires-7..2 PTM transform -> write 729 outputs straight into
//      f16 MFMA A-fragment layout (T=idx/27, j=idx%27, m=4*P0+P1).
//   E. main: AF -> 108 VGPRs once/wave; per 16-elem group 27 MFMAs +
//      non-divergent VALU contraction (round-10-verified); 8 groups/wave.
// ============================================================================

typedef _Float16 v8hf __attribute__((ext_vector_type(8)));
typedef float v4f __attribute__((ext_vector_type(4)));

struct cpx { float re, im; };
__device__ __forceinline__ cpx cmul(cpx a, cpx b) {
    return {a.re * b.re - a.im * b.im, a.re * b.im + a.im * b.re};
}

__device__ __forceinline__ cpx pget(int a, int i, int j) {
    static const float RE[4][4] = {{1, 0, 0, 1}, {0, 1, 1, 0},
                                   {0, 0, 0, 0}, {1, 0, 0, -1}};
    static const float IM[4][4] = {{0, 0, 0, 0}, {0, 0, 0, 0},
                                   {0, -1, 1, 0}, {0, 0, 0, 0}};
    cpx r; r.re = RE[a][i * 2 + j]; r.im = IM[a][i * 2 + j];
    return r;
}

// PTM entry (gate g = l*8+w, row a, col b) = 0.5 Re Tr(sig_b G^dag sig_a G)
__device__ float ptm_entry(const float* __restrict__ theta, int g, int a, int b) {
    const int l = g >> 3, w = g & 7;
    const float phi = theta[(l * 8 + w) * 3 + 0];
    const float th  = theta[(l * 8 + w) * 3 + 1];
    const float om  = theta[(l * 8 + w) * 3 + 2];
    const float c = cosf(0.5f * th), s = sinf(0.5f * th);
    const float ps = 0.5f * (phi + om), ms = 0.5f * (phi - om);
    cpx G[2][2];
    G[0][0] = {c * cosf(ps), -c * sinf(ps)};
    G[0][1] = {-s * cosf(ms), -s * sinf(ms)};
    G[1][0] = {s * cosf(ms), -s * sinf(ms)};
    G[1][1] = {c * cosf(ps), c * sinf(ps)};
    cpx M1[2][2], H[2][2];
#pragma unroll
    for (int i = 0; i < 2; ++i)
#pragma unroll
        for (int j = 0; j < 2; ++j) {
            cpx acc{0.f, 0.f};
#pragma unroll
            for (int k = 0; k < 2; ++k) {
                cpx t = cmul(pget(a, i, k), G[k][j]);
                acc.re += t.re; acc.im += t.im;
            }
            M1[i][j] = acc;
        }
#pragma unroll
    for (int i = 0; i < 2; ++i)
#pragma unroll
        for (int j = 0; j < 2; ++j) {
            cpx acc{0.f, 0.f};
#pragma unroll
            for (int k = 0; k < 2; ++k) {
                cpx gc{G[k][i].re, -G[k][i].im};
                cpx t = cmul(gc, M1[k][j]);
                acc.re += t.re; acc.im += t.im;
            }
            H[i][j] = acc;
        }
    float tr = 0.f;
#pragma unroll
    for (int i = 0; i < 2; ++i)
#pragma unroll
        for (int j = 0; j < 2; ++j) {
            cpx pb = pget(b, i, j);
            tr += pb.re * H[j][i].re - pb.im * H[j][i].im;
        }
    return 0.5f * tr;
}

__device__ void cnot_entry(int pr, int cand, int* CIDX, float* CSGN) {
    const int pc = pr >> 2, pt = pr & 3;
    const int a = cand >> 2, b2 = cand & 3;
    const int perm[4] = {0, 1, 3, 2};
    float ov = 0.f;
#pragma unroll
    for (int r = 0; r < 4; ++r)
#pragma unroll
        for (int c2 = 0; c2 < 4; ++c2) {
            const int rp = perm[r], cp = perm[c2];
            cpx Rv = cmul(pget(pc, rp >> 1, cp >> 1), pget(pt, rp & 1, cp & 1));
            cpx Kv = cmul(pget(a, r >> 1, c2 >> 1), pget(b2, r & 1, c2 & 1));
            ov += Kv.re * Rv.re + Kv.im * Rv.im;
        }
    ov *= 0.25f;
    if (ov > 0.5f) { CIDX[pr] = cand; CSGN[pr] = 1.f; }
    else if (ov < -0.5f) { CIDX[pr] = cand; CSGN[pr] = -1.f; }
}

__device__ __forceinline__ int ring_conj(int cur, int r, const int* CIDX,
                                         const float* CSGN, float& sg) {
    for (int w = 7; w >= 0; --w) {
        const int tw = (w + r) & 7;
        const int pc = (cur >> (2 * w)) & 3;
        const int pt = (cur >> (2 * tw)) & 3;
        const int q = pc * 4 + pt;
        const int nq = CIDX[q];
        sg *= CSGN[q];
        cur = (cur & ~((3 << (2 * w)) | (3 << (2 * tw))))
            | ((nq >> 2) << (2 * w)) | ((nq & 3) << (2 * tw));
    }
    return cur;
}

// ---------------------------------------------------------------------------
// The single kernel. 256 threads/block; grid = ngroups/32 blocks (32 groups
// per block = 8 per wave). launch_bounds(256,1): full VGPR budget, no spill.
// ---------------------------------------------------------------------------
__global__ __launch_bounds__(256, 1) void k_one(const float* __restrict__ x,
                                                const float* __restrict__ theta,
                                                float* __restrict__ out,
                                                int ngroups) {
    // LDS: AF (6912 ints) | Wa 4096 | Wb 3072 | TR 256 | CSGN 16 | CIDX 16
    __shared__ int   AFl[6912];
    __shared__ float Wa[4096];
    __shared__ float Wb[3072];
    __shared__ float TR[256];
    __shared__ float CSGN[16];
    __shared__ int   CIDX[16];
    __shared__ int   S1k, S1n;
    __shared__ float S1sgn;
    __shared__ int   S1w[8], S1l[8];

    const int tid = threadIdx.x;

    // ---- A: tables + zero AF ----
    TR[tid] = ptm_entry(theta, tid >> 4, (tid >> 2) & 3, tid & 3);
    cnot_entry(tid >> 4, tid & 15, CIDX, CSGN);
#pragma unroll
    for (int u = tid; u < 6912; u += 256) AFl[u] = 0;
    __syncthreads();

    // ---- B: S1 = Ring2^dag Z0 Ring2 ----
    if (tid == 0) {
        float sg = 1.f;
        int cur = ring_conj(3 /* Z wire0 */, 2, CIDX, CSGN, sg);
        int k = 0;
        for (int w = 0; w < 8; ++w) {
            const int ltr = (cur >> (2 * w)) & 3;
            if (ltr != 0) { S1w[k] = w; S1l[k] = ltr; ++k; }
        }
        int n = 1;
        for (int i = 0; i < k; ++i) n *= 3;
        S1sgn = sg; S1k = k; S1n = n;
    }
    __syncthreads();
    const int k1 = S1k, n1 = S1n;

    // ---- C: enumerate strings once into registers (26/thread) ----
    // pk = (d4<<4) | (a0<<2) | a1 ; cf = coefficient.
    int   pk[26];
    float cf[26];
#pragma unroll
    for (int i = 0; i < 26; ++i) {
        pk[i] = -1;
        cf[i] = 0.f;
        const int t = tid + 256 * i;
        if (t < n1) {
            float c = S1sgn;
            int s = 0;
            int tt = t;
#pragma unroll
            for (int ii = 0; ii < 8; ++ii) {
                if (ii < k1) {
                    const int bl = tt % 3 + 1;  // X=1,Y=2,Z=3
                    tt /= 3;
                    c *= TR[(8 + S1w[ii]) * 16 + S1l[ii] * 4 + bl];
                    s |= bl << (2 * S1w[ii]);
                }
            }
            float sg = 1.f;
            s = ring_conj(s, 1, CIDX, CSGN, sg);
            c *= sg;
            const int a0 = s & 3, a1 = (s >> 2) & 3;
            int d4 = 0;
#pragma unroll
            for (int w = 2; w < 8; ++w)
                d4 |= ((s >> (2 * w)) & 3) << (2 * (7 - w));
            pk[i] = (d4 << 4) | (a0 << 2) | a1;
            cf[i] = c;
        }
    }

    // ---- D: 9 (P0,P1) rounds -> AF ----
    _Float16* AF16 = (_Float16*)AFl;
    for (int p = 0; p < 9; ++p) {
        const int P0 = p / 3, P1 = p % 3;
        const int let0 = (P0 == 0) ? 0 : ((P0 == 1) ? 3 : 2);
        const int let1 = (P1 == 0) ? 0 : ((P1 == 1) ? 3 : 2);

        for (int u = tid; u < 4096; u += 256) Wa[u] = 0.f;
        __syncthreads();

#pragma unroll
        for (int i = 0; i < 26; ++i) {
            if (pk[i] >= 0) {
                const int a0 = (pk[i] >> 2) & 3, a1 = pk[i] & 3;
                const int d4 = pk[i] >> 4;
                const float v = cf[i] * TR[a0 * 4 + let0] * TR[16 + a1 * 4 + let1];
                atomicAdd(&Wa[d4], v);
            }
        }
        __syncthreads();

        // 6 PTM stages, wires 7..2. invariant idx = q3 + 3^tl*(a + 4r).
        const int P3c[6] = {1, 3, 9, 27, 81, 243};
        const int N4c[6] = {1024, 256, 64, 16, 4, 1};
#pragma unroll
        for (int tl = 0; tl < 6; ++tl) {
            const int w = 7 - tl;
            const float* src = (tl & 1) ? Wb : Wa;
            float* dst = (tl & 1) ? Wa : Wb;
            const int p3 = P3c[tl];
            const int Nout = p3 * 3 * N4c[tl];
            for (int idx = tid; idx < Nout; idx += 256) {
                const int q3 = idx % p3;
                const int rest = idx / p3;
                const int P = rest % 3;
                const int r = rest / 3;
                const int let = (P == 0) ? 0 : ((P == 1) ? 3 : 2);
                const float* ib = src + q3 + p3 * 4 * r;
                dst[idx] = ib[0] * TR[w * 16 + 0 + let]
                         + ib[p3] * TR[w * 16 + 4 + let]
                         + ib[2 * p3] * TR[w * 16 + 8 + let]
                         + ib[3 * p3] * TR[w * 16 + 12 + let];
            }
            __syncthreads();
        }
        // final 729 in Wa. idx = k2*243+k3*81+k4*27+k5*9+k6*3+k7.
        // T = idx/27, j = idx%27, m = 4*P0+P1.
        const int m = 4 * P0 + P1;
        for (int idx = tid; idx < 729; idx += 256) {
            const int T = idx / 27, j = idx % 27;
            const int h = (T * 64 + (j >> 3) * 16 + m) * 8 + (j & 7);
            AF16[h] = (_Float16)Wa[idx];
        }
        __syncthreads();
    }

    // ---- E: main (round-10-verified non-divergent contraction) ----
    const int lane = tid & 63;
    const int q = lane >> 4, e = lane & 15;
    const bool q0b = (q == 0), q1b = (q == 1), q2b = (q == 2);
    const v8hf* AFp = (const v8hf*)AFl;
    v8hf af[27];
#pragma unroll
    for (int t = 0; t < 27; ++t) af[t] = AFp[t * 64 + lane];

    const int wave = blockIdx.x * 4 + (tid >> 6);

    // preload x for all 8 groups of this wave
    float4 xs0[8], xs1[8];
#pragma unroll
    for (int gi = 0; gi < 8; ++gi) {
        const int g = wave * 8 + gi;
        if (g < ngroups) {
            const float4* xp = (const float4*)(x + (size_t)(g * 16 + e) * 8);
            xs0[gi] = xp[0];
            xs1[gi] = xp[1];
        }
    }

#pragma unroll 1
    for (int gi = 0; gi < 8; ++gi) {
        const int g = wave * 8 + gi;
        if (g >= ngroups) break;
        const int b = g * 16 + e;
        const float4 xa = xs0[gi], xb = xs1[gi];

        float cw[8], msw[8];
        {
            const float xv[8] = {xa.x, xa.y, xa.z, xa.w, xb.x, xb.y, xb.z, xb.w};
#pragma unroll
            for (int w = 0; w < 8; ++w) {
                float sv, cv;
                __sincosf(xv[w], &sv, &cv);
                cw[w] = cv;
                msw[w] = -sv;
            }
        }

        float F2[27];
        {
            const float m5v[3] = {1.f, cw[5], msw[5]};
            const float m6v[3] = {1.f, cw[6], msw[6]};
            const float m7v[3] = {1.f, cw[7], msw[7]};
#pragma unroll
            for (int a = 0; a < 3; ++a)
#pragma unroll
                for (int b2 = 0; b2 < 3; ++b2) {
                    const float pp = m5v[a] * m6v[b2];
#pragma unroll
                    for (int c2 = 0; c2 < 3; ++c2)
                        F2[(a * 3 + b2) * 3 + c2] = pp * m7v[c2];
                }
        }
        v8hf bf;
#pragma unroll
        for (int jj = 0; jj < 8; ++jj) {
            const float c0 = F2[jj];
            const float c1 = F2[jj + 8];
            const float c2 = F2[jj + 16];
            const float c3 = (jj < 3) ? F2[jj + 24] : 0.f;
            const float v = q0b ? c0 : (q1b ? c1 : (q2b ? c2 : c3));
            bf[jj] = (_Float16)v;
        }

        const v4f zero = {0.f, 0.f, 0.f, 0.f};
        float h[9];
#pragma unroll
        for (int t = 0; t < 27; ++t) {
            const int a = t / 9, b2 = (t / 3) % 3, c2 = t % 3;
            v4f acc = __builtin_amdgcn_mfma_f32_16x16x32_f16(af[t], bf, zero, 0, 0, 0);
            float f = fmaf(cw[1], acc[1], acc[0]);
            f = fmaf(msw[1], acc[2], f);
            if (c2 == 0)      h[a * 3 + b2] = f;
            else if (c2 == 1) h[a * 3 + b2] = fmaf(cw[4], f, h[a * 3 + b2]);
            else              h[a * 3 + b2] = fmaf(msw[4], f, h[a * 3 + b2]);
        }
        float e0 = fmaf(cw[3], h[1], h[0]); e0 = fmaf(msw[3], h[2], e0);
        float e1 = fmaf(cw[3], h[4], h[3]); e1 = fmaf(msw[3], h[5], e1);
        float e2 = fmaf(cw[3], h[7], h[6]); e2 = fmaf(msw[3], h[8], e2);
        float ev = fmaf(cw[2], e1, e0);
        ev = fmaf(msw[2], e2, ev);
        const float g0 = q0b ? 1.f : (q1b ? cw[0] : (q2b ? msw[0] : 0.f));
        ev *= g0;

        ev += __shfl_xor(ev, 16, 64);
        ev += __shfl_xor(ev, 32, 64);
        if (lane < 16) out[b] = (ev + 1.f) * 0.5f;
    }
}

// ============================================================================
// Fallback: round-1 direct statevector simulator (odd batch sizes).
// ============================================================================
struct c32 { float x, y; };

__device__ __forceinline__ c32 shfl_xor_c(c32 v, int mask) {
    c32 r;
    r.x = __shfl_xor(v.x, mask, 64);
    r.y = __shfl_xor(v.y, mask, 64);
    return r;
}
__device__ __forceinline__ c32 cmadd2(c32 ga, c32 a, c32 gp, c32 p) {
    c32 n;
    n.x = ga.x * a.x - ga.y * a.y + gp.x * p.x - gp.y * p.y;
    n.y = ga.x * a.y + ga.y * a.x + gp.x * p.y + gp.y * p.x;
    return n;
}
__device__ __forceinline__ c32 rx_mix(float c, float s, c32 a, c32 p) {
    c32 n;
    n.x = c * a.x + s * p.y;
    n.y = c * a.y - s * p.x;
    return n;
}
__device__ __forceinline__ void apply_rx(c32 st[4], int lane, int bb, float c, float s) {
    if (bb < 6) {
#pragma unroll
        for (int r = 0; r < 4; ++r) {
            c32 p = shfl_xor_c(st[r], 1 << bb);
            st[r] = rx_mix(c, s, st[r], p);
        }
    } else if (bb == 6) {
        c32 n0 = rx_mix(c, s, st[0], st[1]);
        c32 n1 = rx_mix(c, s, st[1], st[0]);
        c32 n2 = rx_mix(c, s, st[2], st[3]);
        c32 n3 = rx_mix(c, s, st[3], st[2]);
        st[0] = n0; st[1] = n1; st[2] = n2; st[3] = n3;
    } else {
        c32 n0 = rx_mix(c, s, st[0], st[2]);
        c32 n2 = rx_mix(c, s, st[2], st[0]);
        c32 n1 = rx_mix(c, s, st[1], st[3]);
        c32 n3 = rx_mix(c, s, st[3], st[1]);
        st[0] = n0; st[1] = n1; st[2] = n2; st[3] = n3;
    }
}
__device__ __forceinline__ void apply_rot(c32 st[4], int lane, int bb,
                                          c32 g00, c32 g01, c32 g10, c32 g11) {
    if (bb < 6) {
#pragma unroll
        for (int r = 0; r < 4; ++r) {
            c32 p = shfl_xor_c(st[r], 1 << bb);
            bool hi = (lane >> bb) & 1;
            c32 ga, gp;
            ga.x = hi ? g11.x : g00.x;
            ga.y = hi ? g11.y : g00.y;
            gp.x = hi ? g10.x : g01.x;
            gp.y = hi ? g10.y : g01.y;
            st[r] = cmadd2(ga, st[r], gp, p);
        }
    } else if (bb == 6) {
        c32 n0 = cmadd2(g00, st[0], g01, st[1]);
        c32 n1 = cmadd2(g10, st[0], g11, st[1]);
        c32 n2 = cmadd2(g00, st[2], g01, st[3]);
        c32 n3 = cmadd2(g10, st[2], g11, st[3]);
        st[0] = n0; st[1] = n1; st[2] = n2; st[3] = n3;
    } else {
        c32 n0 = cmadd2(g00, st[0], g01, st[2]);
        c32 n2 = cmadd2(g10, st[0], g11, st[2]);
        c32 n1 = cmadd2(g00, st[1], g01, st[3]);
        c32 n3 = cmadd2(g10, st[1], g11, st[3]);
        st[0] = n0; st[1] = n1; st[2] = n2; st[3] = n3;
    }
}
__device__ __forceinline__ void cswap(bool c, c32& a, c32& b) {
    c32 t = a;
    a.x = c ? b.x : a.x; a.y = c ? b.y : a.y;
    b.x = c ? t.x : b.x; b.y = c ? t.y : b.y;
}
__device__ __forceinline__ void apply_cnot(c32 st[4], int lane, int bc, int bt) {
    if (bt < 6) {
        if (bc < 6) {
            bool ctrl = (lane >> bc) & 1;
#pragma unroll
            for (int r = 0; r < 4; ++r) {
                c32 p = shfl_xor_c(st[r], 1 << bt);
                st[r].x = ctrl ? p.x : st[r].x;
                st[r].y = ctrl ? p.y : st[r].y;
            }
        } else {
#pragma unroll
            for (int r = 0; r < 4; ++r) {
                if ((r >> (bc - 6)) & 1) st[r] = shfl_xor_c(st[r], 1 << bt);
            }
        }
    } else {
        if (bc < 6) {
            bool ctrl = (lane >> bc) & 1;
            if (bt == 6) { cswap(ctrl, st[0], st[1]); cswap(ctrl, st[2], st[3]); }
            else         { cswap(ctrl, st[0], st[2]); cswap(ctrl, st[1], st[3]); }
        } else {
            if (bc == 7 && bt == 6) { c32 t = st[2]; st[2] = st[3]; st[3] = t; }
            else if (bc == 6 && bt == 7) { c32 t = st[1]; st[1] = st[3]; st[3] = t; }
        }
    }
}
__global__ __launch_bounds__(256) void qsim_kernel(const float* __restrict__ x,
                                                   const float* __restrict__ theta,
                                                   float* __restrict__ out,
                                                   int batch) {
    __shared__ float rot[2 * 8 * 8];
    const int t = threadIdx.x;
    if (t < 16) {
        const int l = t >> 3, w = t & 7;
        const float phi = theta[(l * 8 + w) * 3 + 0];
        const float th  = theta[(l * 8 + w) * 3 + 1];
        const float om  = theta[(l * 8 + w) * 3 + 2];
        const float c = cosf(0.5f * th), s = sinf(0.5f * th);
        const float p = 0.5f * (phi + om), m = 0.5f * (phi - om);
        float* g = &rot[t * 8];
        g[0] = c * cosf(p);  g[1] = -c * sinf(p);
        g[2] = -s * cosf(m); g[3] = -s * sinf(m);
        g[4] = s * cosf(m);  g[5] = -s * sinf(m);
        g[6] = c * cosf(p);  g[7] = c * sinf(p);
    }
    __syncthreads();
    const int lane = t & 63;
    const int b = blockIdx.x * 4 + (t >> 6);
    if (b >= batch) return;
    float c8 = 0.f, s8 = 0.f;
    if (lane < 8) {
        const float xv = 0.5f * x[b * 8 + lane];
        c8 = cosf(xv); s8 = sinf(xv);
    }
    c32 st[4];
#pragma unroll
    for (int r = 0; r < 4; ++r) { st[r].x = 0.f; st[r].y = 0.f; }
    if (lane == 0) st[0].x = 1.f;
#pragma unroll
    for (int w = 0; w < 8; ++w) {
        const float c = __shfl(c8, w, 64);
        const float s = __shfl(s8, w, 64);
        apply_rx(st, lane, 7 - w, c, s);
    }
#pragma unroll
    for (int l = 0; l < 2; ++l) {
#pragma unroll
        for (int w = 0; w < 8; ++w) {
            const float* g = &rot[(l * 8 + w) * 8];
            c32 g00{g[0], g[1]}, g01{g[2], g[3]}, g10{g[4], g[5]}, g11{g[6], g[7]};
            apply_rot(st, lane, 7 - w, g00, g01, g10, g11);
        }
        const int rr = l + 1;
#pragma unroll
        for (int w = 0; w < 8; ++w) apply_cnot(st, lane, 7 - w, 7 - ((w + rr) & 7));
    }
    float v = st[0].x * st[0].x + st[0].y * st[0].y
            + st[1].x * st[1].x + st[1].y * st[1].y
            - st[2].x * st[2].x - st[2].y * st[2].y
            - st[3].x * st[3].x - st[3].y * st[3].y;
#pragma unroll
    for (int off = 32; off > 0; off >>= 1) v += __shfl_xor(v, off, 64);
    if (lane == 0) out[b] = (v + 1.f) * 0.5f;
}

// ============================================================================
extern "C" void kernel_launch(void* const* d_in, const int* in_sizes, int n_in,
                              void* d_out, int out_size, void* d_ws, size_t ws_size,
                              hipStream_t stream) {
    const float* x     = (const float*)d_in[0];
    const float* theta = (const float*)d_in[1];
    float* out = (float*)d_out;
    const int batch = in_sizes[0] / 8;

    if ((batch & 15) == 0) {
        const int ngroups = batch / 16;            // 8192
        const int blocks = (ngroups + 31) / 32;    // 32 groups/block -> 256
        k_one<<<dim3(blocks), dim3(256), 0, stream>>>(x, theta, out, ngroups);
    } else {
        qsim_kernel<<<dim3((batch + 3) / 4), dim3(256), 0, stream>>>(x, theta, out, batch);
    }
}

// Round 12
// 69.964 us; speedup vs baseline: 1.8523x; 1.8523x over previous
//
#include <hip/hip_runtime.h>

// ============================================================================
// ev(b) = F1(b)^T * A * F2(b); A fixed (theta batch-uniform).
// k_prep3 (10 blocks x 1024, fully independent — no flags/spins):
//   blocks 0-8: own (P0,P1) pair: tables -> enumerate <=6561 post-ring
//     strings -> project through wire-0/1 PTM rows -> scatter-add dense 4^6
//     LDS tensor -> 6-stage wires-7..2 PTM transform -> write 729 values
//     straight into ws AF (f16 fragment layout, own m-row, 2-byte stores).
//   block 9: zero all AF slots never written by blocks 0-8 (disjoint).
// k_main7 (512 x 256): AF LDS-staged then hoisted to 108 VGPRs/wave;
//   per 16-elem group 27 MFMAs + non-divergent contraction (r10-verified);
//   4 groups/wave.
// ============================================================================

typedef _Float16 v8hf __attribute__((ext_vector_type(8)));
typedef float v4f __attribute__((ext_vector_type(4)));

struct cpx { float re, im; };
__device__ __forceinline__ cpx cmul(cpx a, cpx b) {
    return {a.re * b.re - a.im * b.im, a.re * b.im + a.im * b.re};
}

__device__ __forceinline__ cpx pget(int a, int i, int j) {
    static const float RE[4][4] = {{1, 0, 0, 1}, {0, 1, 1, 0},
                                   {0, 0, 0, 0}, {1, 0, 0, -1}};
    static const float IM[4][4] = {{0, 0, 0, 0}, {0, 0, 0, 0},
                                   {0, -1, 1, 0}, {0, 0, 0, 0}};
    cpx r; r.re = RE[a][i * 2 + j]; r.im = IM[a][i * 2 + j];
    return r;
}

// PTM entry (gate g = l*8+w, row a, col b) = 0.5 Re Tr(sig_b G^dag sig_a G)
__device__ float ptm_entry(const float* __restrict__ theta, int g, int a, int b) {
    const int l = g >> 3, w = g & 7;
    const float phi = theta[(l * 8 + w) * 3 + 0];
    const float th  = theta[(l * 8 + w) * 3 + 1];
    const float om  = theta[(l * 8 + w) * 3 + 2];
    const float c = cosf(0.5f * th), s = sinf(0.5f * th);
    const float ps = 0.5f * (phi + om), ms = 0.5f * (phi - om);
    cpx G[2][2];
    G[0][0] = {c * cosf(ps), -c * sinf(ps)};
    G[0][1] = {-s * cosf(ms), -s * sinf(ms)};
    G[1][0] = {s * cosf(ms), -s * sinf(ms)};
    G[1][1] = {c * cosf(ps), c * sinf(ps)};
    cpx M1[2][2], H[2][2];
#pragma unroll
    for (int i = 0; i < 2; ++i)
#pragma unroll
        for (int j = 0; j < 2; ++j) {
            cpx acc{0.f, 0.f};
#pragma unroll
            for (int k = 0; k < 2; ++k) {
                cpx t = cmul(pget(a, i, k), G[k][j]);
                acc.re += t.re; acc.im += t.im;
            }
            M1[i][j] = acc;
        }
#pragma unroll
    for (int i = 0; i < 2; ++i)
#pragma unroll
        for (int j = 0; j < 2; ++j) {
            cpx acc{0.f, 0.f};
#pragma unroll
            for (int k = 0; k < 2; ++k) {
                cpx gc{G[k][i].re, -G[k][i].im};
                cpx t = cmul(gc, M1[k][j]);
                acc.re += t.re; acc.im += t.im;
            }
            H[i][j] = acc;
        }
    float tr = 0.f;
#pragma unroll
    for (int i = 0; i < 2; ++i)
#pragma unroll
        for (int j = 0; j < 2; ++j) {
            cpx pb = pget(b, i, j);
            tr += pb.re * H[j][i].re - pb.im * H[j][i].im;
        }
    return 0.5f * tr;
}

__device__ void cnot_entry(int pr, int cand, int* CIDX, float* CSGN) {
    const int pc = pr >> 2, pt = pr & 3;
    const int a = cand >> 2, b2 = cand & 3;
    const int perm[4] = {0, 1, 3, 2};
    float ov = 0.f;
#pragma unroll
    for (int r = 0; r < 4; ++r)
#pragma unroll
        for (int c2 = 0; c2 < 4; ++c2) {
            const int rp = perm[r], cp = perm[c2];
            cpx Rv = cmul(pget(pc, rp >> 1, cp >> 1), pget(pt, rp & 1, cp & 1));
            cpx Kv = cmul(pget(a, r >> 1, c2 >> 1), pget(b2, r & 1, c2 & 1));
            ov += Kv.re * Rv.re + Kv.im * Rv.im;
        }
    ov *= 0.25f;
    if (ov > 0.5f) { CIDX[pr] = cand; CSGN[pr] = 1.f; }
    else if (ov < -0.5f) { CIDX[pr] = cand; CSGN[pr] = -1.f; }
}

__device__ __forceinline__ int ring_conj(int cur, int r, const int* CIDX,
                                         const float* CSGN, float& sg) {
    for (int w = 7; w >= 0; --w) {
        const int tw = (w + r) & 7;
        const int pc = (cur >> (2 * w)) & 3;
        const int pt = (cur >> (2 * tw)) & 3;
        const int q = pc * 4 + pt;
        const int nq = CIDX[q];
        sg *= CSGN[q];
        cur = (cur & ~((3 << (2 * w)) | (3 << (2 * tw))))
            | ((nq >> 2) << (2 * w)) | ((nq & 3) << (2 * tw));
    }
    return cur;
}

// ws: AF = 6912 ints (13824 halfs)
#define WS_FLOATS_NEEDED 6912

// ---------------------------------------------------------------------------
// k_prep3: 10 independent blocks x 1024.
// ---------------------------------------------------------------------------
__global__ __launch_bounds__(1024) void k_prep3(const float* __restrict__ theta,
                                                float* __restrict__ ws) {
    _Float16* AF16 = (_Float16*)ws;
    const int tid = threadIdx.x;
    const int blk = blockIdx.x;

    if (blk == 9) {
        // zero every AF half not written by blocks 0-8 (disjoint addresses)
        for (int h = tid; h < 27 * 64 * 8; h += 1024) {
            const int L = (h >> 3) & 63;
            const int jj = h & 7;
            const int m = L & 15;
            const int j = (L >> 4) * 8 + jj;
            const bool valid = (m < 12) && ((m & 3) < 3) && (j < 27);
            if (!valid) AF16[h] = (_Float16)0.f;
        }
        return;
    }

    __shared__ float Wa[4096];
    __shared__ float Wb[3072];
    __shared__ float TR[256];
    __shared__ float CSGN[16];
    __shared__ int   CIDX[16];
    __shared__ int   S1k, S1n;
    __shared__ float S1sgn;
    __shared__ int   S1w[8], S1l[8];

    const int P0 = blk / 3, P1 = blk % 3;
    const int let0 = (P0 == 0) ? 0 : ((P0 == 1) ? 3 : 2);
    const int let1 = (P1 == 0) ? 0 : ((P1 == 1) ? 3 : 2);

    // tables (verified r7/r10)
    if (tid < 256) TR[tid] = ptm_entry(theta, tid >> 4, (tid >> 2) & 3, tid & 3);
    else if (tid < 512) {
        const int r = tid - 256;
        cnot_entry(r >> 4, r & 15, CIDX, CSGN);
    }
    for (int i = tid; i < 4096; i += 1024) Wa[i] = 0.f;
    __syncthreads();

    // S1 = Ring2^dag Z0 Ring2
    if (tid == 0) {
        float sg = 1.f;
        int cur = ring_conj(3 /* Z wire0 */, 2, CIDX, CSGN, sg);
        int k = 0;
        for (int w = 0; w < 8; ++w) {
            const int ltr = (cur >> (2 * w)) & 3;
            if (ltr != 0) { S1w[k] = w; S1l[k] = ltr; ++k; }
        }
        int n = 1;
        for (int i = 0; i < k; ++i) n *= 3;
        S1sgn = sg; S1k = k; S1n = n;
    }
    __syncthreads();
    const int k1 = S1k, n1 = S1n;

    // enumerate + layer-1 expand + ring-1 conj + project wires 0,1 + scatter
    // (math verified r11)
    for (int t = tid; t < n1; t += 1024) {
        float c = S1sgn;
        int s = 0;
        int tt = t;
        for (int i = 0; i < k1; ++i) {
            const int bl = tt % 3 + 1;  // X=1,Y=2,Z=3
            tt /= 3;
            c *= TR[(8 + S1w[i]) * 16 + S1l[i] * 4 + bl];
            s |= bl << (2 * S1w[i]);
        }
        float sg = 1.f;
        s = ring_conj(s, 1, CIDX, CSGN, sg);
        c *= sg;
        const int a0 = s & 3, a1 = (s >> 2) & 3;
        int d4 = 0;
#pragma unroll
        for (int w = 2; w < 8; ++w)
            d4 |= ((s >> (2 * w)) & 3) << (2 * (7 - w));
        const float v = c * TR[a0 * 4 + let0] * TR[16 + a1 * 4 + let1];
        atomicAdd(&Wa[d4], v);
    }
    __syncthreads();

    // 6 PTM stages, wires 7..2 (verified). idx = q3 + 3^tl*(a + 4r).
    const int P3c[6] = {1, 3, 9, 27, 81, 243};
    const int N4c[6] = {1024, 256, 64, 16, 4, 1};
#pragma unroll
    for (int tl = 0; tl < 6; ++tl) {
        const int w = 7 - tl;
        const float* src = (tl & 1) ? Wb : Wa;
        float* dst = (tl & 1) ? Wa : Wb;
        const int p3 = P3c[tl];
        const int Nout = p3 * 3 * N4c[tl];
        for (int idx = tid; idx < Nout; idx += 1024) {
            const int q3 = idx % p3;
            const int rest = idx / p3;
            const int P = rest % 3;
            const int r = rest / 3;
            const int let = (P == 0) ? 0 : ((P == 1) ? 3 : 2);
            const float* ib = src + q3 + p3 * 4 * r;
            dst[idx] = ib[0] * TR[w * 16 + 0 + let]
                     + ib[p3] * TR[w * 16 + 4 + let]
                     + ib[2 * p3] * TR[w * 16 + 8 + let]
                     + ib[3 * p3] * TR[w * 16 + 12 + let];
        }
        __syncthreads();
    }

    // final 729 in Wa -> own m-row of AF (2-byte stores; layout verified r11)
    const int m = 4 * P0 + P1;
    for (int idx = tid; idx < 729; idx += 1024) {
        const int T = idx / 27, j = idx % 27;
        const int h = (T * 64 + (j >> 3) * 16 + m) * 8 + (j & 7);
        AF16[h] = (_Float16)Wa[idx];
    }
}

// ---------------------------------------------------------------------------
// k_main7: r10-verified contraction; AF hoisted to registers once per wave.
// ---------------------------------------------------------------------------
__global__ __launch_bounds__(256) void k_main7(const float* __restrict__ x,
                                               const int* __restrict__ wsAF,
                                               float* __restrict__ out,
                                               int ngroups) {
    __shared__ int AFl[6912];
    const int tid = threadIdx.x;
    for (int u = tid; u < 6912; u += 256) AFl[u] = wsAF[u];
    __syncthreads();

    const int lane = tid & 63;
    const int q = lane >> 4, e = lane & 15;
    const bool q0b = (q == 0), q1b = (q == 1), q2b = (q == 2);

    // hoist the 27 A-fragments into registers (108 VGPRs, compile-time idx)
    const v8hf* AFp = (const v8hf*)AFl;
    v8hf af[27];
#pragma unroll
    for (int t = 0; t < 27; ++t) af[t] = AFp[t * 64 + lane];

    const int wave = blockIdx.x * 4 + (tid >> 6);

#pragma unroll 1
    for (int gi = 0; gi < 4; ++gi) {
        const int g = wave * 4 + gi;
        if (g >= ngroups) break;
        const int b = g * 16 + e;
        const float4* xp = (const float4*)(x + (size_t)b * 8);
        const float4 xa = xp[0], xb = xp[1];

        float cw[8], msw[8];
        {
            const float xv[8] = {xa.x, xa.y, xa.z, xa.w, xb.x, xb.y, xb.z, xb.w};
#pragma unroll
            for (int w = 0; w < 8; ++w) {
                float sv, cv;
                __sincosf(xv[w], &sv, &cv);
                cw[w] = cv;
                msw[w] = -sv;
            }
        }

        float F2[27];
        {
            const float m5v[3] = {1.f, cw[5], msw[5]};
            const float m6v[3] = {1.f, cw[6], msw[6]};
            const float m7v[3] = {1.f, cw[7], msw[7]};
#pragma unroll
            for (int a = 0; a < 3; ++a)
#pragma unroll
                for (int b2 = 0; b2 < 3; ++b2) {
                    const float pp = m5v[a] * m6v[b2];
#pragma unroll
                    for (int c2 = 0; c2 < 3; ++c2)
                        F2[(a * 3 + b2) * 3 + c2] = pp * m7v[c2];
                }
        }
        v8hf bf;
#pragma unroll
        for (int jj = 0; jj < 8; ++jj) {
            const float c0 = F2[jj];
            const float c1 = F2[jj + 8];
            const float c2 = F2[jj + 16];
            const float c3 = (jj < 3) ? F2[jj + 24] : 0.f;
            const float v = q0b ? c0 : (q1b ? c1 : (q2b ? c2 : c3));
            bf[jj] = (_Float16)v;
        }

        const v4f zero = {0.f, 0.f, 0.f, 0.f};
        float h[9];
#pragma unroll
        for (int t = 0; t < 27; ++t) {
            const int a = t / 9, b2 = (t / 3) % 3, c2 = t % 3;
            v4f acc = __builtin_amdgcn_mfma_f32_16x16x32_f16(af[t], bf, zero, 0, 0, 0);
            float f = fmaf(cw[1], acc[1], acc[0]);
            f = fmaf(msw[1], acc[2], f);
            if (c2 == 0)      h[a * 3 + b2] = f;
            else if (c2 == 1) h[a * 3 + b2] = fmaf(cw[4], f, h[a * 3 + b2]);
            else              h[a * 3 + b2] = fmaf(msw[4], f, h[a * 3 + b2]);
        }
        float e0 = fmaf(cw[3], h[1], h[0]); e0 = fmaf(msw[3], h[2], e0);
        float e1 = fmaf(cw[3], h[4], h[3]); e1 = fmaf(msw[3], h[5], e1);
        float e2 = fmaf(cw[3], h[7], h[6]); e2 = fmaf(msw[3], h[8], e2);
        float ev = fmaf(cw[2], e1, e0);
        ev = fmaf(msw[2], e2, ev);
        const float g0 = q0b ? 1.f : (q1b ? cw[0] : (q2b ? msw[0] : 0.f));
        ev *= g0;

        ev += __shfl_xor(ev, 16, 64);
        ev += __shfl_xor(ev, 32, 64);
        if (lane < 16) out[b] = (ev + 1.f) * 0.5f;
    }
}

// ============================================================================
// Fallback: round-1 direct statevector simulator (odd batch sizes / tiny ws).
// ============================================================================
struct c32 { float x, y; };

__device__ __forceinline__ c32 shfl_xor_c(c32 v, int mask) {
    c32 r;
    r.x = __shfl_xor(v.x, mask, 64);
    r.y = __shfl_xor(v.y, mask, 64);
    return r;
}
__device__ __forceinline__ c32 cmadd2(c32 ga, c32 a, c32 gp, c32 p) {
    c32 n;
    n.x = ga.x * a.x - ga.y * a.y + gp.x * p.x - gp.y * p.y;
    n.y = ga.x * a.y + ga.y * a.x + gp.x * p.y + gp.y * p.x;
    return n;
}
__device__ __forceinline__ c32 rx_mix(float c, float s, c32 a, c32 p) {
    c32 n;
    n.x = c * a.x + s * p.y;
    n.y = c * a.y - s * p.x;
    return n;
}
__device__ __forceinline__ void apply_rx(c32 st[4], int lane, int bb, float c, float s) {
    if (bb < 6) {
#pragma unroll
        for (int r = 0; r < 4; ++r) {
            c32 p = shfl_xor_c(st[r], 1 << bb);
            st[r] = rx_mix(c, s, st[r], p);
        }
    } else if (bb == 6) {
        c32 n0 = rx_mix(c, s, st[0], st[1]);
        c32 n1 = rx_mix(c, s, st[1], st[0]);
        c32 n2 = rx_mix(c, s, st[2], st[3]);
        c32 n3 = rx_mix(c, s, st[3], st[2]);
        st[0] = n0; st[1] = n1; st[2] = n2; st[3] = n3;
    } else {
        c32 n0 = rx_mix(c, s, st[0], st[2]);
        c32 n2 = rx_mix(c, s, st[2], st[0]);
        c32 n1 = rx_mix(c, s, st[1], st[3]);
        c32 n3 = rx_mix(c, s, st[3], st[1]);
        st[0] = n0; st[1] = n1; st[2] = n2; st[3] = n3;
    }
}
__device__ __forceinline__ void apply_rot(c32 st[4], int lane, int bb,
                                          c32 g00, c32 g01, c32 g10, c32 g11) {
    if (bb < 6) {
#pragma unroll
        for (int r = 0; r < 4; ++r) {
            c32 p = shfl_xor_c(st[r], 1 << bb);
            bool hi = (lane >> bb) & 1;
            c32 ga, gp;
            ga.x = hi ? g11.x : g00.x;
            ga.y = hi ? g11.y : g00.y;
            gp.x = hi ? g10.x : g01.x;
            gp.y = hi ? g10.y : g01.y;
            st[r] = cmadd2(ga, st[r], gp, p);
        }
    } else if (bb == 6) {
        c32 n0 = cmadd2(g00, st[0], g01, st[1]);
        c32 n1 = cmadd2(g10, st[0], g11, st[1]);
        c32 n2 = cmadd2(g00, st[2], g01, st[3]);
        c32 n3 = cmadd2(g10, st[2], g11, st[3]);
        st[0] = n0; st[1] = n1; st[2] = n2; st[3] = n3;
    } else {
        c32 n0 = cmadd2(g00, st[0], g01, st[2]);
        c32 n2 = cmadd2(g10, st[0], g11, st[2]);
        c32 n1 = cmadd2(g00, st[1], g01, st[3]);
        c32 n3 = cmadd2(g10, st[1], g11, st[3]);
        st[0] = n0; st[1] = n1; st[2] = n2; st[3] = n3;
    }
}
__device__ __forceinline__ void cswap(bool c, c32& a, c32& b) {
    c32 t = a;
    a.x = c ? b.x : a.x; a.y = c ? b.y : a.y;
    b.x = c ? t.x : b.x; b.y = c ? t.y : b.y;
}
__device__ __forceinline__ void apply_cnot(c32 st[4], int lane, int bc, int bt) {
    if (bt < 6) {
        if (bc < 6) {
            bool ctrl = (lane >> bc) & 1;
#pragma unroll
            for (int r = 0; r < 4; ++r) {
                c32 p = shfl_xor_c(st[r], 1 << bt);
                st[r].x = ctrl ? p.x : st[r].x;
                st[r].y = ctrl ? p.y : st[r].y;
            }
        } else {
#pragma unroll
            for (int r = 0; r < 4; ++r) {
                if ((r >> (bc - 6)) & 1) st[r] = shfl_xor_c(st[r], 1 << bt);
            }
        }
    } else {
        if (bc < 6) {
            bool ctrl = (lane >> bc) & 1;
            if (bt == 6) { cswap(ctrl, st[0], st[1]); cswap(ctrl, st[2], st[3]); }
            else         { cswap(ctrl, st[0], st[2]); cswap(ctrl, st[1], st[3]); }
        } else {
            if (bc == 7 && bt == 6) { c32 t = st[2]; st[2] = st[3]; st[3] = t; }
            else if (bc == 6 && bt == 7) { c32 t = st[1]; st[1] = st[3]; st[3] = t; }
        }
    }
}
__global__ __launch_bounds__(256) void qsim_kernel(const float* __restrict__ x,
                                                   const float* __restrict__ theta,
                                                   float* __restrict__ out,
                                                   int batch) {
    __shared__ float rot[2 * 8 * 8];
    const int t = threadIdx.x;
    if (t < 16) {
        const int l = t >> 3, w = t & 7;
        const float phi = theta[(l * 8 + w) * 3 + 0];
        const float th  = theta[(l * 8 + w) * 3 + 1];
        const float om  = theta[(l * 8 + w) * 3 + 2];
        const float c = cosf(0.5f * th), s = sinf(0.5f * th);
        const float p = 0.5f * (phi + om), m = 0.5f * (phi - om);
        float* g = &rot[t * 8];
        g[0] = c * cosf(p);  g[1] = -c * sinf(p);
        g[2] = -s * cosf(m); g[3] = -s * sinf(m);
        g[4] = s * cosf(m);  g[5] = -s * sinf(m);
        g[6] = c * cosf(p);  g[7] = c * sinf(p);
    }
    __syncthreads();
    const int lane = t & 63;
    const int b = blockIdx.x * 4 + (t >> 6);
    if (b >= batch) return;
    float c8 = 0.f, s8 = 0.f;
    if (lane < 8) {
        const float xv = 0.5f * x[b * 8 + lane];
        c8 = cosf(xv); s8 = sinf(xv);
    }
    c32 st[4];
#pragma unroll
    for (int r = 0; r < 4; ++r) { st[r].x = 0.f; st[r].y = 0.f; }
    if (lane == 0) st[0].x = 1.f;
#pragma unroll
    for (int w = 0; w < 8; ++w) {
        const float c = __shfl(c8, w, 64);
        const float s = __shfl(s8, w, 64);
        apply_rx(st, lane, 7 - w, c, s);
    }
#pragma unroll
    for (int l = 0; l < 2; ++l) {
#pragma unroll
        for (int w = 0; w < 8; ++w) {
            const float* g = &rot[(l * 8 + w) * 8];
            c32 g00{g[0], g[1]}, g01{g[2], g[3]}, g10{g[4], g[5]}, g11{g[6], g[7]};
            apply_rot(st, lane, 7 - w, g00, g01, g10, g11);
        }
        const int rr = l + 1;
#pragma unroll
        for (int w = 0; w < 8; ++w) apply_cnot(st, lane, 7 - w, 7 - ((w + rr) & 7));
    }
    float v = st[0].x * st[0].x + st[0].y * st[0].y
            + st[1].x * st[1].x + st[1].y * st[1].y
            - st[2].x * st[2].x - st[2].y * st[2].y
            - st[3].x * st[3].x - st[3].y * st[3].y;
#pragma unroll
    for (int off = 32; off > 0; off >>= 1) v += __shfl_xor(v, off, 64);
    if (lane == 0) out[b] = (v + 1.f) * 0.5f;
}

// ============================================================================
extern "C" void kernel_launch(void* const* d_in, const int* in_sizes, int n_in,
                              void* d_out, int out_size, void* d_ws, size_t ws_size,
                              hipStream_t stream) {
    const float* x     = (const float*)d_in[0];
    const float* theta = (const float*)d_in[1];
    float* out = (float*)d_out;
    const int batch = in_sizes[0] / 8;

    if (ws_size >= (size_t)WS_FLOATS_NEEDED * 4 + 256 && (batch & 15) == 0) {
        float* ws = (float*)d_ws;
        k_prep3<<<dim3(10), dim3(1024), 0, stream>>>(theta, ws);
        const int ngroups = batch / 16;  // 8192
        k_main7<<<dim3(512), dim3(256), 0, stream>>>(
            x, (const int*)ws, out, ngroups);
    } else {
        qsim_kernel<<<dim3((batch + 3) / 4), dim3(256), 0, stream>>>(x, theta, out, batch);
    }
}

// Round 13
// 69.286 us; speedup vs baseline: 1.8704x; 1.0098x over previous
//
#include <hip/hip_runtime.h>

// ============================================================================
// ev(b) = F1(b)^T * A * F2(b); A fixed (theta batch-uniform).
// k_prep3 (10 blocks x 1024, fully independent — verified r12):
//   blocks 0-8: own (P0,P1) pair -> 729 values -> ws AF (f16 frag layout).
//   block 9: zero unused AF slots.
// k_main8 (1024 x 256): AF staged to LDS; fragments read from LDS at each
//   MFMA (no register hoist -> ~90 VGPR -> 4+ waves/SIMD); 2 groups/wave;
//   non-divergent contraction (r10/r12-verified).
// ============================================================================

typedef _Float16 v8hf __attribute__((ext_vector_type(8)));
typedef float v4f __attribute__((ext_vector_type(4)));

struct cpx { float re, im; };
__device__ __forceinline__ cpx cmul(cpx a, cpx b) {
    return {a.re * b.re - a.im * b.im, a.re * b.im + a.im * b.re};
}

__device__ __forceinline__ cpx pget(int a, int i, int j) {
    static const float RE[4][4] = {{1, 0, 0, 1}, {0, 1, 1, 0},
                                   {0, 0, 0, 0}, {1, 0, 0, -1}};
    static const float IM[4][4] = {{0, 0, 0, 0}, {0, 0, 0, 0},
                                   {0, -1, 1, 0}, {0, 0, 0, 0}};
    cpx r; r.re = RE[a][i * 2 + j]; r.im = IM[a][i * 2 + j];
    return r;
}

// PTM entry (gate g = l*8+w, row a, col b) = 0.5 Re Tr(sig_b G^dag sig_a G)
__device__ float ptm_entry(const float* __restrict__ theta, int g, int a, int b) {
    const int l = g >> 3, w = g & 7;
    const float phi = theta[(l * 8 + w) * 3 + 0];
    const float th  = theta[(l * 8 + w) * 3 + 1];
    const float om  = theta[(l * 8 + w) * 3 + 2];
    const float c = cosf(0.5f * th), s = sinf(0.5f * th);
    const float ps = 0.5f * (phi + om), ms = 0.5f * (phi - om);
    cpx G[2][2];
    G[0][0] = {c * cosf(ps), -c * sinf(ps)};
    G[0][1] = {-s * cosf(ms), -s * sinf(ms)};
    G[1][0] = {s * cosf(ms), -s * sinf(ms)};
    G[1][1] = {c * cosf(ps), c * sinf(ps)};
    cpx M1[2][2], H[2][2];
#pragma unroll
    for (int i = 0; i < 2; ++i)
#pragma unroll
        for (int j = 0; j < 2; ++j) {
            cpx acc{0.f, 0.f};
#pragma unroll
            for (int k = 0; k < 2; ++k) {
                cpx t = cmul(pget(a, i, k), G[k][j]);
                acc.re += t.re; acc.im += t.im;
            }
            M1[i][j] = acc;
        }
#pragma unroll
    for (int i = 0; i < 2; ++i)
#pragma unroll
        for (int j = 0; j < 2; ++j) {
            cpx acc{0.f, 0.f};
#pragma unroll
            for (int k = 0; k < 2; ++k) {
                cpx gc{G[k][i].re, -G[k][i].im};
                cpx t = cmul(gc, M1[k][j]);
                acc.re += t.re; acc.im += t.im;
            }
            H[i][j] = acc;
        }
    float tr = 0.f;
#pragma unroll
    for (int i = 0; i < 2; ++i)
#pragma unroll
        for (int j = 0; j < 2; ++j) {
            cpx pb = pget(b, i, j);
            tr += pb.re * H[j][i].re - pb.im * H[j][i].im;
        }
    return 0.5f * tr;
}

__device__ void cnot_entry(int pr, int cand, int* CIDX, float* CSGN) {
    const int pc = pr >> 2, pt = pr & 3;
    const int a = cand >> 2, b2 = cand & 3;
    const int perm[4] = {0, 1, 3, 2};
    float ov = 0.f;
#pragma unroll
    for (int r = 0; r < 4; ++r)
#pragma unroll
        for (int c2 = 0; c2 < 4; ++c2) {
            const int rp = perm[r], cp = perm[c2];
            cpx Rv = cmul(pget(pc, rp >> 1, cp >> 1), pget(pt, rp & 1, cp & 1));
            cpx Kv = cmul(pget(a, r >> 1, c2 >> 1), pget(b2, r & 1, c2 & 1));
            ov += Kv.re * Rv.re + Kv.im * Rv.im;
        }
    ov *= 0.25f;
    if (ov > 0.5f) { CIDX[pr] = cand; CSGN[pr] = 1.f; }
    else if (ov < -0.5f) { CIDX[pr] = cand; CSGN[pr] = -1.f; }
}

__device__ __forceinline__ int ring_conj(int cur, int r, const int* CIDX,
                                         const float* CSGN, float& sg) {
    for (int w = 7; w >= 0; --w) {
        const int tw = (w + r) & 7;
        const int pc = (cur >> (2 * w)) & 3;
        const int pt = (cur >> (2 * tw)) & 3;
        const int q = pc * 4 + pt;
        const int nq = CIDX[q];
        sg *= CSGN[q];
        cur = (cur & ~((3 << (2 * w)) | (3 << (2 * tw))))
            | ((nq >> 2) << (2 * w)) | ((nq & 3) << (2 * tw));
    }
    return cur;
}

// ws: AF = 6912 ints (13824 halfs)
#define WS_FLOATS_NEEDED 6912

// ---------------------------------------------------------------------------
// k_prep3: 10 independent blocks x 1024 (verified r12, unchanged).
// ---------------------------------------------------------------------------
__global__ __launch_bounds__(1024) void k_prep3(const float* __restrict__ theta,
                                                float* __restrict__ ws) {
    _Float16* AF16 = (_Float16*)ws;
    const int tid = threadIdx.x;
    const int blk = blockIdx.x;

    if (blk == 9) {
        for (int h = tid; h < 27 * 64 * 8; h += 1024) {
            const int L = (h >> 3) & 63;
            const int jj = h & 7;
            const int m = L & 15;
            const int j = (L >> 4) * 8 + jj;
            const bool valid = (m < 12) && ((m & 3) < 3) && (j < 27);
            if (!valid) AF16[h] = (_Float16)0.f;
        }
        return;
    }

    __shared__ float Wa[4096];
    __shared__ float Wb[3072];
    __shared__ float TR[256];
    __shared__ float CSGN[16];
    __shared__ int   CIDX[16];
    __shared__ int   S1k, S1n;
    __shared__ float S1sgn;
    __shared__ int   S1w[8], S1l[8];

    const int P0 = blk / 3, P1 = blk % 3;
    const int let0 = (P0 == 0) ? 0 : ((P0 == 1) ? 3 : 2);
    const int let1 = (P1 == 0) ? 0 : ((P1 == 1) ? 3 : 2);

    if (tid < 256) TR[tid] = ptm_entry(theta, tid >> 4, (tid >> 2) & 3, tid & 3);
    else if (tid < 512) {
        const int r = tid - 256;
        cnot_entry(r >> 4, r & 15, CIDX, CSGN);
    }
    for (int i = tid; i < 4096; i += 1024) Wa[i] = 0.f;
    __syncthreads();

    if (tid == 0) {
        float sg = 1.f;
        int cur = ring_conj(3 /* Z wire0 */, 2, CIDX, CSGN, sg);
        int k = 0;
        for (int w = 0; w < 8; ++w) {
            const int ltr = (cur >> (2 * w)) & 3;
            if (ltr != 0) { S1w[k] = w; S1l[k] = ltr; ++k; }
        }
        int n = 1;
        for (int i = 0; i < k; ++i) n *= 3;
        S1sgn = sg; S1k = k; S1n = n;
    }
    __syncthreads();
    const int k1 = S1k, n1 = S1n;

    for (int t = tid; t < n1; t += 1024) {
        float c = S1sgn;
        int s = 0;
        int tt = t;
        for (int i = 0; i < k1; ++i) {
            const int bl = tt % 3 + 1;  // X=1,Y=2,Z=3
            tt /= 3;
            c *= TR[(8 + S1w[i]) * 16 + S1l[i] * 4 + bl];
            s |= bl << (2 * S1w[i]);
        }
        float sg = 1.f;
        s = ring_conj(s, 1, CIDX, CSGN, sg);
        c *= sg;
        const int a0 = s & 3, a1 = (s >> 2) & 3;
        int d4 = 0;
#pragma unroll
        for (int w = 2; w < 8; ++w)
            d4 |= ((s >> (2 * w)) & 3) << (2 * (7 - w));
        const float v = c * TR[a0 * 4 + let0] * TR[16 + a1 * 4 + let1];
        atomicAdd(&Wa[d4], v);
    }
    __syncthreads();

    const int P3c[6] = {1, 3, 9, 27, 81, 243};
    const int N4c[6] = {1024, 256, 64, 16, 4, 1};
#pragma unroll
    for (int tl = 0; tl < 6; ++tl) {
        const int w = 7 - tl;
        const float* src = (tl & 1) ? Wb : Wa;
        float* dst = (tl & 1) ? Wa : Wb;
        const int p3 = P3c[tl];
        const int Nout = p3 * 3 * N4c[tl];
        for (int idx = tid; idx < Nout; idx += 1024) {
            const int q3 = idx % p3;
            const int rest = idx / p3;
            const int P = rest % 3;
            const int r = rest / 3;
            const int let = (P == 0) ? 0 : ((P == 1) ? 3 : 2);
            const float* ib = src + q3 + p3 * 4 * r;
            dst[idx] = ib[0] * TR[w * 16 + 0 + let]
                     + ib[p3] * TR[w * 16 + 4 + let]
                     + ib[2 * p3] * TR[w * 16 + 8 + let]
                     + ib[3 * p3] * TR[w * 16 + 12 + let];
        }
        __syncthreads();
    }

    const int m = 4 * P0 + P1;
    for (int idx = tid; idx < 729; idx += 1024) {
        const int T = idx / 27, j = idx % 27;
        const int h = (T * 64 + (j >> 3) * 16 + m) * 8 + (j & 7);
        AF16[h] = (_Float16)Wa[idx];
    }
}

// ---------------------------------------------------------------------------
// k_main8: fragments from LDS (no hoist), 2 groups/wave, high occupancy.
// ---------------------------------------------------------------------------
__global__ __launch_bounds__(256) void k_main8(const float* __restrict__ x,
                                               const int* __restrict__ wsAF,
                                               float* __restrict__ out,
                                               int ngroups) {
    __shared__ int AFl[6912];
    const int tid = threadIdx.x;
    for (int u = tid; u < 6912; u += 256) AFl[u] = wsAF[u];
    __syncthreads();

    const int lane = tid & 63;
    const int q = lane >> 4, e = lane & 15;
    const bool q0b = (q == 0), q1b = (q == 1), q2b = (q == 2);
    const v8hf* AFp = (const v8hf*)AFl;
    const int wave = blockIdx.x * 4 + (tid >> 6);

#pragma unroll 1
    for (int gi = 0; gi < 2; ++gi) {
        const int g = wave * 2 + gi;
        if (g >= ngroups) break;
        const int b = g * 16 + e;
        const float4* xp = (const float4*)(x + (size_t)b * 8);
        const float4 xa = xp[0], xb = xp[1];

        float cw[8], msw[8];
        {
            const float xv[8] = {xa.x, xa.y, xa.z, xa.w, xb.x, xb.y, xb.z, xb.w};
#pragma unroll
            for (int w = 0; w < 8; ++w) {
                float sv, cv;
                __sincosf(xv[w], &sv, &cv);
                cw[w] = cv;
                msw[w] = -sv;
            }
        }

        float F2[27];
        {
            const float m5v[3] = {1.f, cw[5], msw[5]};
            const float m6v[3] = {1.f, cw[6], msw[6]};
            const float m7v[3] = {1.f, cw[7], msw[7]};
#pragma unroll
            for (int a = 0; a < 3; ++a)
#pragma unroll
                for (int b2 = 0; b2 < 3; ++b2) {
                    const float pp = m5v[a] * m6v[b2];
#pragma unroll
                    for (int c2 = 0; c2 < 3; ++c2)
                        F2[(a * 3 + b2) * 3 + c2] = pp * m7v[c2];
                }
        }
        v8hf bf;
#pragma unroll
        for (int jj = 0; jj < 8; ++jj) {
            const float c0 = F2[jj];
            const float c1 = F2[jj + 8];
            const float c2 = F2[jj + 16];
            const float c3 = (jj < 3) ? F2[jj + 24] : 0.f;
            const float v = q0b ? c0 : (q1b ? c1 : (q2b ? c2 : c3));
            bf[jj] = (_Float16)v;
        }

        const v4f zero = {0.f, 0.f, 0.f, 0.f};
        float h[9];
#pragma unroll
        for (int t = 0; t < 27; ++t) {
            const int a = t / 9, b2 = (t / 3) % 3, c2 = t % 3;
            v4f acc = __builtin_amdgcn_mfma_f32_16x16x32_f16(
                AFp[t * 64 + lane], bf, zero, 0, 0, 0);
            float f = fmaf(cw[1], acc[1], acc[0]);
            f = fmaf(msw[1], acc[2], f);
            if (c2 == 0)      h[a * 3 + b2] = f;
            else if (c2 == 1) h[a * 3 + b2] = fmaf(cw[4], f, h[a * 3 + b2]);
            else              h[a * 3 + b2] = fmaf(msw[4], f, h[a * 3 + b2]);
        }
        float e0 = fmaf(cw[3], h[1], h[0]); e0 = fmaf(msw[3], h[2], e0);
        float e1 = fmaf(cw[3], h[4], h[3]); e1 = fmaf(msw[3], h[5], e1);
        float e2 = fmaf(cw[3], h[7], h[6]); e2 = fmaf(msw[3], h[8], e2);
        float ev = fmaf(cw[2], e1, e0);
        ev = fmaf(msw[2], e2, ev);
        const float g0 = q0b ? 1.f : (q1b ? cw[0] : (q2b ? msw[0] : 0.f));
        ev *= g0;

        ev += __shfl_xor(ev, 16, 64);
        ev += __shfl_xor(ev, 32, 64);
        if (lane < 16) out[b] = (ev + 1.f) * 0.5f;
    }
}

// ============================================================================
// Fallback: round-1 direct statevector simulator (odd batch sizes / tiny ws).
// ============================================================================
struct c32 { float x, y; };

__device__ __forceinline__ c32 shfl_xor_c(c32 v, int mask) {
    c32 r;
    r.x = __shfl_xor(v.x, mask, 64);
    r.y = __shfl_xor(v.y, mask, 64);
    return r;
}
__device__ __forceinline__ c32 cmadd2(c32 ga, c32 a, c32 gp, c32 p) {
    c32 n;
    n.x = ga.x * a.x - ga.y * a.y + gp.x * p.x - gp.y * p.y;
    n.y = ga.x * a.y + ga.y * a.x + gp.x * p.y + gp.y * p.x;
    return n;
}
__device__ __forceinline__ c32 rx_mix(float c, float s, c32 a, c32 p) {
    c32 n;
    n.x = c * a.x + s * p.y;
    n.y = c * a.y - s * p.x;
    return n;
}
__device__ __forceinline__ void apply_rx(c32 st[4], int lane, int bb, float c, float s) {
    if (bb < 6) {
#pragma unroll
        for (int r = 0; r < 4; ++r) {
            c32 p = shfl_xor_c(st[r], 1 << bb);
            st[r] = rx_mix(c, s, st[r], p);
        }
    } else if (bb == 6) {
        c32 n0 = rx_mix(c, s, st[0], st[1]);
        c32 n1 = rx_mix(c, s, st[1], st[0]);
        c32 n2 = rx_mix(c, s, st[2], st[3]);
        c32 n3 = rx_mix(c, s, st[3], st[2]);
        st[0] = n0; st[1] = n1; st[2] = n2; st[3] = n3;
    } else {
        c32 n0 = rx_mix(c, s, st[0], st[2]);
        c32 n2 = rx_mix(c, s, st[2], st[0]);
        c32 n1 = rx_mix(c, s, st[1], st[3]);
        c32 n3 = rx_mix(c, s, st[3], st[1]);
        st[0] = n0; st[1] = n1; st[2] = n2; st[3] = n3;
    }
}
__device__ __forceinline__ void apply_rot(c32 st[4], int lane, int bb,
                                          c32 g00, c32 g01, c32 g10, c32 g11) {
    if (bb < 6) {
#pragma unroll
        for (int r = 0; r < 4; ++r) {
            c32 p = shfl_xor_c(st[r], 1 << bb);
            bool hi = (lane >> bb) & 1;
            c32 ga, gp;
            ga.x = hi ? g11.x : g00.x;
            ga.y = hi ? g11.y : g00.y;
            gp.x = hi ? g10.x : g01.x;
            gp.y = hi ? g10.y : g01.y;
            st[r] = cmadd2(ga, st[r], gp, p);
        }
    } else if (bb == 6) {
        c32 n0 = cmadd2(g00, st[0], g01, st[1]);
        c32 n1 = cmadd2(g10, st[0], g11, st[1]);
        c32 n2 = cmadd2(g00, st[2], g01, st[3]);
        c32 n3 = cmadd2(g10, st[2], g11, st[3]);
        st[0] = n0; st[1] = n1; st[2] = n2; st[3] = n3;
    } else {
        c32 n0 = cmadd2(g00, st[0], g01, st[2]);
        c32 n2 = cmadd2(g10, st[0], g11, st[2]);
        c32 n1 = cmadd2(g00, st[1], g01, st[3]);
        c32 n3 = cmadd2(g10, st[1], g11, st[3]);
        st[0] = n0; st[1] = n1; st[2] = n2; st[3] = n3;
    }
}
__device__ __forceinline__ void cswap(bool c, c32& a, c32& b) {
    c32 t = a;
    a.x = c ? b.x : a.x; a.y = c ? b.y : a.y;
    b.x = c ? t.x : b.x; b.y = c ? t.y : b.y;
}
__device__ __forceinline__ void apply_cnot(c32 st[4], int lane, int bc, int bt) {
    if (bt < 6) {
        if (bc < 6) {
            bool ctrl = (lane >> bc) & 1;
#pragma unroll
            for (int r = 0; r < 4; ++r) {
                c32 p = shfl_xor_c(st[r], 1 << bt);
                st[r].x = ctrl ? p.x : st[r].x;
                st[r].y = ctrl ? p.y : st[r].y;
            }
        } else {
#pragma unroll
            for (int r = 0; r < 4; ++r) {
                if ((r >> (bc - 6)) & 1) st[r] = shfl_xor_c(st[r], 1 << bt);
            }
        }
    } else {
        if (bc < 6) {
            bool ctrl = (lane >> bc) & 1;
            if (bt == 6) { cswap(ctrl, st[0], st[1]); cswap(ctrl, st[2], st[3]); }
            else         { cswap(ctrl, st[0], st[2]); cswap(ctrl, st[1], st[3]); }
        } else {
            if (bc == 7 && bt == 6) { c32 t = st[2]; st[2] = st[3]; st[3] = t; }
            else if (bc == 6 && bt == 7) { c32 t = st[1]; st[1] = st[3]; st[3] = t; }
        }
    }
}
__global__ __launch_bounds__(256) void qsim_kernel(const float* __restrict__ x,
                                                   const float* __restrict__ theta,
                                                   float* __restrict__ out,
                                                   int batch) {
    __shared__ float rot[2 * 8 * 8];
    const int t = threadIdx.x;
    if (t < 16) {
        const int l = t >> 3, w = t & 7;
        const float phi = theta[(l * 8 + w) * 3 + 0];
        const float th  = theta[(l * 8 + w) * 3 + 1];
        const float om  = theta[(l * 8 + w) * 3 + 2];
        const float c = cosf(0.5f * th), s = sinf(0.5f * th);
        const float p = 0.5f * (phi + om), m = 0.5f * (phi - om);
        float* g = &rot[t * 8];
        g[0] = c * cosf(p);  g[1] = -c * sinf(p);
        g[2] = -s * cosf(m); g[3] = -s * sinf(m);
        g[4] = s * cosf(m);  g[5] = -s * sinf(m);
        g[6] = c * cosf(p);  g[7] = c * sinf(p);
    }
    __syncthreads();
    const int lane = t & 63;
    const int b = blockIdx.x * 4 + (t >> 6);
    if (b >= batch) return;
    float c8 = 0.f, s8 = 0.f;
    if (lane < 8) {
        const float xv = 0.5f * x[b * 8 + lane];
        c8 = cosf(xv); s8 = sinf(xv);
    }
    c32 st[4];
#pragma unroll
    for (int r = 0; r < 4; ++r) { st[r].x = 0.f; st[r].y = 0.f; }
    if (lane == 0) st[0].x = 1.f;
#pragma unroll
    for (int w = 0; w < 8; ++w) {
        const float c = __shfl(c8, w, 64);
        const float s = __shfl(s8, w, 64);
        apply_rx(st, lane, 7 - w, c, s);
    }
#pragma unroll
    for (int l = 0; l < 2; ++l) {
#pragma unroll
        for (int w = 0; w < 8; ++w) {
            const float* g = &rot[(l * 8 + w) * 8];
            c32 g00{g[0], g[1]}, g01{g[2], g[3]}, g10{g[4], g[5]}, g11{g[6], g[7]};
            apply_rot(st, lane, 7 - w, g00, g01, g10, g11);
        }
        const int rr = l + 1;
#pragma unroll
        for (int w = 0; w < 8; ++w) apply_cnot(st, lane, 7 - w, 7 - ((w + rr) & 7));
    }
    float v = st[0].x * st[0].x + st[0].y * st[0].y
            + st[1].x * st[1].x + st[1].y * st[1].y
            - st[2].x * st[2].x - st[2].y * st[2].y
            - st[3].x * st[3].x - st[3].y * st[3].y;
#pragma unroll
    for (int off = 32; off > 0; off >>= 1) v += __shfl_xor(v, off, 64);
    if (lane == 0) out[b] = (v + 1.f) * 0.5f;
}

// ============================================================================
extern "C" void kernel_launch(void* const* d_in, const int* in_sizes, int n_in,
                              void* d_out, int out_size, void* d_ws, size_t ws_size,
                              hipStream_t stream) {
    const float* x     = (const float*)d_in[0];
    const float* theta = (const float*)d_in[1];
    float* out = (float*)d_out;
    const int batch = in_sizes[0] / 8;

    if (ws_size >= (size_t)WS_FLOATS_NEEDED * 4 + 256 && (batch & 15) == 0) {
        float* ws = (float*)d_ws;
        k_prep3<<<dim3(10), dim3(1024), 0, stream>>>(theta, ws);
        const int ngroups = batch / 16;                 // 8192
        const int blocks = (ngroups + 7) / 8;           // 2 groups/wave -> 1024
        k_main8<<<dim3(blocks), dim3(256), 0, stream>>>(
            x, (const int*)ws, out, ngroups);
    } else {
        qsim_kernel<<<dim3((batch + 3) / 4), dim3(256), 0, stream>>>(x, theta, out, batch);
    }
}